// Round 19
// baseline (47.580 us; speedup 1.0000x reference)
//
#include <hip/hip_runtime.h>
#include <math.h>

// Problem constants (fixed shapes from reference)
#define BATCH   8
#define HGRID   64
#define WGRID   64
#define DDIM    256
#define NPTS    1024
#define ROWS    65          // HGRID + 1 (NaN pad row 0)
#define COLS    65
#define KWIN    15          // (2*R_WIN+1)*(2*C_WIN+1) = 3*5
#define BN      (BATCH*NPTS)

#define PIDS_PER_BLK 8
#define THREADS      512    // 8 waves; Phase B: ONE pid per wave
#define PR_PITCH     260

typedef __attribute__((ext_vector_type(8))) short bf16x8;
typedef __attribute__((ext_vector_type(4))) float f32x4;

// ---------------------------------------------------------------------------
// Kernel 1 (prep_q): q fp32 -> bf16 (truncate). 2M elems; 1024 x 256 x 8.
// qb is hot in L2/L3 when the fused kernel gathers from it.
// ---------------------------------------------------------------------------
__global__ __launch_bounds__(256) void prep_q(const float* __restrict__ q,
                                              ushort* __restrict__ qb) {
    const int i = (blockIdx.x * 256 + threadIdx.x) * 8;
    const float4 a = *reinterpret_cast<const float4*>(&q[i]);
    const float4 b = *reinterpret_cast<const float4*>(&q[i + 4]);
    ushort4 lo, hi;
    lo.x = (ushort)(__float_as_uint(a.x) >> 16);
    lo.y = (ushort)(__float_as_uint(a.y) >> 16);
    lo.z = (ushort)(__float_as_uint(a.z) >> 16);
    lo.w = (ushort)(__float_as_uint(a.w) >> 16);
    hi.x = (ushort)(__float_as_uint(b.x) >> 16);
    hi.y = (ushort)(__float_as_uint(b.y) >> 16);
    hi.z = (ushort)(__float_as_uint(b.z) >> 16);
    hi.w = (ushort)(__float_as_uint(b.w) >> 16);
    *reinterpret_cast<ushort4*>(&qb[i])     = lo;
    *reinterpret_cast<ushort4*>(&qb[i + 4]) = hi;
}

// ---------------------------------------------------------------------------
// Kernel 2 (fused v14): 8 pids/block, 1 pid per wave, grid 1024 (XCD-swizzled
// so XCD x serves batch x). Phase A: R6-proven 8-pid M-pad split-bf16 MFMA
// (fat fp32+convert form — v11 proved the VALU hides W-load latency).
// Phase B: bf16 q gathers — ALL 15 rows in registers (2 VGPR each), no LDS
// staging, no fences; one vmcnt(0); unpack via shift/mask.
// LDS = Pr[8][260] = 8.3KB only -> up to 4 blocks/CU = 32 waves/CU.
// ---------------------------------------------------------------------------
__global__ __launch_bounds__(THREADS, 4) void fused_local_attn(
        const ushort* __restrict__ qb,
        const float* __restrict__ c_t,
        const float* __restrict__ p_t,
        const float* __restrict__ W,
        float* __restrict__ out) {

    __shared__ __align__(16) float Pr[PIDS_PER_BLK][PR_PITCH];   // 8.3 KB

    const int t    = threadIdx.x;
    const int w    = t >> 6;          // wave 0..7
    const int lane = t & 63;
    const int l15  = lane & 15;
    const int g    = lane >> 4;       // k-group 0..3
    const int bid  = blockIdx.x;
    const int wk   = (bid & 7) * 128 + (bid >> 3);   // XCD x <- batch x
    const int pid0 = wk * PIDS_PER_BLK;
    const int dq   = w * 32;          // this wave's 32-col d-slice

    // ---------------- Phase A: proj into LDS (R6-proven M-pad) ------------
    f32x4 acc0 = (f32x4)0.f;
    f32x4 acc1 = (f32x4)0.f;

    const float* ap  = &c_t[(size_t)(pid0 + (l15 & 7)) * DDIM + g * 8];
    const float* wp0 = &W[(size_t)(g * 8) * DDIM + dq + l15];        // df=0
    const float* wp1 = wp0 + 16;                                      // df=1

    #pragma unroll 2
    for (int kt = 0; kt < 8; ++kt) {
        const float4 a01 = *reinterpret_cast<const float4*>(ap + kt * 32);
        const float4 a23 = *reinterpret_cast<const float4*>(ap + kt * 32 + 4);
        const float af[8] = {a01.x, a01.y, a01.z, a01.w, a23.x, a23.y, a23.z, a23.w};
        union { bf16x8 v; unsigned u[4]; } AH, AL;
        #pragma unroll
        for (int i = 0; i < 4; ++i) {
            const unsigned u0 = __float_as_uint(af[2 * i]);
            const unsigned u1 = __float_as_uint(af[2 * i + 1]);
            AH.u[i] = __builtin_amdgcn_perm(u1, u0, 0x07060302u);
            const float l0 = af[2 * i]     - __uint_as_float(u0 & 0xFFFF0000u);
            const float l1 = af[2 * i + 1] - __uint_as_float(u1 & 0xFFFF0000u);
            AL.u[i] = __builtin_amdgcn_perm(__float_as_uint(l1), __float_as_uint(l0),
                                            0x07060302u);
        }

        #pragma unroll
        for (int df = 0; df < 2; ++df) {
            const float* wp = (df == 0) ? wp0 : wp1;
            float bf[8];
            #pragma unroll
            for (int i = 0; i < 8; ++i)
                bf[i] = wp[(size_t)(kt * 32 + i) * DDIM];
            union { bf16x8 v; unsigned u[4]; } BH, BL;
            #pragma unroll
            for (int i = 0; i < 4; ++i) {
                const unsigned u0 = __float_as_uint(bf[2 * i]);
                const unsigned u1 = __float_as_uint(bf[2 * i + 1]);
                BH.u[i] = __builtin_amdgcn_perm(u1, u0, 0x07060302u);
                const float l0 = bf[2 * i]     - __uint_as_float(u0 & 0xFFFF0000u);
                const float l1 = bf[2 * i + 1] - __uint_as_float(u1 & 0xFFFF0000u);
                BL.u[i] = __builtin_amdgcn_perm(__float_as_uint(l1), __float_as_uint(l0),
                                                0x07060302u);
            }
            f32x4 a = (df == 0) ? acc0 : acc1;
            a = __builtin_amdgcn_mfma_f32_16x16x32_bf16(AH.v, BH.v, a, 0, 0, 0);
            a = __builtin_amdgcn_mfma_f32_16x16x32_bf16(AH.v, BL.v, a, 0, 0, 0);
            a = __builtin_amdgcn_mfma_f32_16x16x32_bf16(AL.v, BH.v, a, 0, 0, 0);
            if (df == 0) acc0 = a; else acc1 = a;
        }
    }

    // C/D layout: col = lane&15, row = (lane>>4)*4 + reg  [m89-verified]
    // Only rows 0..7 are real points (g < 2).
    if (g < 2) {
        #pragma unroll
        for (int r = 0; r < 4; ++r) {
            Pr[g * 4 + r][dq +  0 + l15] = acc0[r];
            Pr[g * 4 + r][dq + 16 + l15] = acc1[r];
        }
    }
    __syncthreads();

    // ---------------- Phase B: attention, 1 pid per wave ------------------
    const int pid = pid0 + w;
    const int b   = pid >> 10;             // / NPTS
    const float4 pr = *reinterpret_cast<const float4*>(&Pr[w][lane * 4]);

    const float2 ppos = *reinterpret_cast<const float2*>(&p_t[pid * 2]);
    const float p0f = ppos.x;
    const float p1f = ppos.y;
    const int p0 = (int)p0f;
    const int p1 = (int)p1f;

    float re[3], ce[5];
    int rowidx[3], colidx[5];
    #pragma unroll
    for (int i = 0; i < 3; ++i) {
        int rr = p0 + i;
        rr = rr > ROWS ? ROWS : rr;
        rr = (rr == ROWS) ? 0 : rr;        // % ROWS
        rowidx[i] = rr;
        const float rf = (float)(rr - 1 > 0 ? rr - 1 : 0);
        const float dr = rf - p0f;         // / R_WIN (=1)
        re[i] = __expf(-2.0f * dr * dr);
    }
    #pragma unroll
    for (int j = 0; j < 5; ++j) {
        int cc = p1 + j - 1;
        cc = cc < 0 ? 0 : (cc > COLS ? COLS : cc);
        cc = (cc == COLS) ? 0 : cc;        // % COLS
        colidx[j] = cc;
        const float cf = (float)(cc - 1 > 0 ? cc - 1 : 0);
        const float dc = (cf - p1f) * 0.5f; // / C_WIN (=2)
        ce[j] = __expf(-2.0f * dc * dc);
    }

    // ---- Issue ALL 15 gathers into registers (bf16: 2 VGPR/row) ----
    uint2 qg[KWIN];
    unsigned vmask = 0;
    #pragma unroll
    for (int k = 0; k < KWIN; ++k) {
        const int i = k / 5, j = k % 5;
        const int rr = rowidx[i];
        const int cc = colidx[j];
        const bool valid = (rr != 0) && (cc != 0);   // wave-uniform
        uint2 v = make_uint2(0u, 0u);
        if (valid) {
            v = *reinterpret_cast<const uint2*>(
                &qb[((size_t)((b * HGRID + rr - 1) * WGRID + cc - 1)) * DDIM + lane * 4]);
            vmask |= (1u << k);
        }
        qg[k] = v;
    }
    asm volatile("s_waitcnt vmcnt(0)" ::: "memory");   // ONE wait for all 15
    #pragma unroll
    for (int k = 0; k < KWIN; ++k)
        asm volatile("" : "+v"(qg[k].x), "+v"(qg[k].y));

    // ---- Scores (unpack bf16 -> f32 via shift/mask) ----
    float score[KWIN];
    #pragma unroll
    for (int k = 0; k < KWIN; ++k) {
        const float d0 = __uint_as_float(qg[k].x << 16);
        const float d1 = __uint_as_float(qg[k].x & 0xFFFF0000u);
        const float d2 = __uint_as_float(qg[k].y << 16);
        const float d3 = __uint_as_float(qg[k].y & 0xFFFF0000u);
        score[k] = fmaf(d0, pr.x, fmaf(d1, pr.y, fmaf(d2, pr.z, d3 * pr.w)));
    }

    // ---- 15 independent butterfly reductions ----
    #pragma unroll
    for (int k = 0; k < KWIN; ++k) {
        float s = score[k];
        #pragma unroll
        for (int off = 32; off; off >>= 1) s += __shfl_xor(s, off, 64);
        score[k] = ((vmask >> k) & 1u) ? s : -INFINITY;
    }

    // ---- Softmax over K=15 (replicated across lanes) ----
    float mx = score[0];
    #pragma unroll
    for (int k = 1; k < KWIN; ++k) mx = fmaxf(mx, score[k]);
    float sum = 0.f;
    #pragma unroll
    for (int k = 0; k < KWIN; ++k) {
        const float e = __expf(score[k] - mx);
        score[k] = e;
        sum += e;
    }
    const float inv = 1.0f / sum;

    // ---- Weighted sum from registers ----
    float ox = 0.f, oy = 0.f, oz = 0.f, ow = 0.f;
    #pragma unroll
    for (int k = 0; k < KWIN; ++k) {
        const int i = k / 5, j = k % 5;
        const float wk2 = score[k] * inv * re[i] * ce[j];
        const float d0 = __uint_as_float(qg[k].x << 16);
        const float d1 = __uint_as_float(qg[k].x & 0xFFFF0000u);
        const float d2 = __uint_as_float(qg[k].y << 16);
        const float d3 = __uint_as_float(qg[k].y & 0xFFFF0000u);
        ox = fmaf(wk2, d0, ox);
        oy = fmaf(wk2, d1, oy);
        oz = fmaf(wk2, d2, oz);
        ow = fmaf(wk2, d3, ow);
    }
    *reinterpret_cast<float4*>(&out[(size_t)pid * DDIM + lane * 4]) =
        make_float4(ox, oy, oz, ow);
}

// ---------------------------------------------------------------------------
extern "C" void kernel_launch(void* const* d_in, const int* in_sizes, int n_in,
                              void* d_out, int out_size, void* d_ws, size_t ws_size,
                              hipStream_t stream) {
    const float* q   = (const float*)d_in[0];
    const float* c_t = (const float*)d_in[1];
    const float* p_t = (const float*)d_in[2];
    const float* W_a = (const float*)d_in[3];
    float* out = (float*)d_out;

    ushort* qb = (ushort*)d_ws;   // 8.4 MB bf16 q

    prep_q<<<BATCH * HGRID * WGRID * DDIM / (256 * 8), 256, 0, stream>>>(q, qb);

    fused_local_attn<<<BN / PIDS_PER_BLK, THREADS, 0, stream>>>(
        qb, c_t, p_t, W_a, out);
}

// Round 21
// 33.762 us; speedup vs baseline: 1.4093x; 1.4093x over previous
//
#include <hip/hip_runtime.h>
#include <math.h>

// Problem constants (fixed shapes from reference)
#define BATCH   8
#define HGRID   64
#define WGRID   64
#define DDIM    256
#define NPTS    1024
#define ROWS    65          // HGRID + 1 (NaN pad row 0)
#define COLS    65
#define KWIN    15          // (2*R_WIN+1)*(2*C_WIN+1) = 3*5
#define BN      (BATCH*NPTS)

#define PIDS_PER_BLK 16
#define THREADS      512    // 8 waves; Phase B: 2 pids per wave
#define NREG         9      // staged q rows in registers
#define NLDS         6      // staged q rows in LDS (per wave slab)

typedef __attribute__((ext_vector_type(8))) short bf16x8;
typedef __attribute__((ext_vector_type(4))) float f32x4;

// Direct-to-LDS 16B/lane: dest = wave-uniform base + lane*16.
__device__ __forceinline__ void gload_lds16(const float* src, float* dst) {
    __builtin_amdgcn_global_load_lds(
        (const __attribute__((address_space(1))) unsigned int*)src,
        (__attribute__((address_space(3))) unsigned int*)dst, 16, 0, 0);
}

// ---------------------------------------------------------------------------
// Fused v16 = v10 verbatim (session best: 33.7us, absmax 0.0156).
//  - 16 pids/block, 512 thr, grid 512; XCD swizzle: XCD x <- batch x
//    (q slab 4MB fits per-XCD L2; FETCH 59->22.7MB measured).
//  - Phase A: fat fp32+convert split-bf16 MFMA (the conversion VALU hides
//    W-load latency — pre-converting regressed twice, R10/R16).
//  - Phase B: hybrid gather engine — 9 reg rows + 6 LDS rows per pid,
//    all 15 loads in flight, ONE vmcnt(0), pins only post-drain.
//  - q stays fp32 (bf16 q fails numerics: score-path error amplified by
//    softmax, R19/R20).
// ---------------------------------------------------------------------------
__global__ __launch_bounds__(THREADS, 4) void fused_local_attn(
        const float* __restrict__ q,
        const float* __restrict__ c_t,
        const float* __restrict__ p_t,
        const float* __restrict__ W,
        float* __restrict__ out) {

    __shared__ __align__(16) float smem[NLDS * DDIM * 8];   // 48 KB
    float (*Pr)[DDIM] = reinterpret_cast<float (*)[DDIM]>(smem);  // 16KB alias

    const int t    = threadIdx.x;
    const int w    = t >> 6;          // wave 0..7
    const int lane = t & 63;
    const int l15  = lane & 15;
    const int g    = lane >> 4;       // k-group 0..3
    const int bid  = blockIdx.x;
    const int wk   = (bid & 7) * 64 + (bid >> 3);   // XCD-aligned work index
    const int pid0 = wk * PIDS_PER_BLK;
    const int dq   = w * 32;          // this wave's 32-col d-slice
    float* qsw = smem + w * (NLDS * DDIM);   // this wave's staging slab

    // ---------------- Phase A: proj into LDS ----------------
    f32x4 acc0 = (f32x4)0.f;
    f32x4 acc1 = (f32x4)0.f;

    const float* ap  = &c_t[(size_t)(pid0 + l15) * DDIM + g * 8];
    const float* wp0 = &W[(size_t)(g * 8) * DDIM + dq + l15];        // df=0
    const float* wp1 = wp0 + 16;                                      // df=1

    #pragma unroll 2
    for (int kt = 0; kt < 8; ++kt) {
        const float4 a01 = *reinterpret_cast<const float4*>(ap + kt * 32);
        const float4 a23 = *reinterpret_cast<const float4*>(ap + kt * 32 + 4);
        const float af[8] = {a01.x, a01.y, a01.z, a01.w, a23.x, a23.y, a23.z, a23.w};
        union { bf16x8 v; unsigned u[4]; } AH, AL;
        #pragma unroll
        for (int i = 0; i < 4; ++i) {
            const unsigned u0 = __float_as_uint(af[2 * i]);
            const unsigned u1 = __float_as_uint(af[2 * i + 1]);
            AH.u[i] = __builtin_amdgcn_perm(u1, u0, 0x07060302u);
            const float l0 = af[2 * i]     - __uint_as_float(u0 & 0xFFFF0000u);
            const float l1 = af[2 * i + 1] - __uint_as_float(u1 & 0xFFFF0000u);
            AL.u[i] = __builtin_amdgcn_perm(__float_as_uint(l1), __float_as_uint(l0),
                                            0x07060302u);
        }

        #pragma unroll
        for (int df = 0; df < 2; ++df) {
            const float* wp = (df == 0) ? wp0 : wp1;
            float bf[8];
            #pragma unroll
            for (int i = 0; i < 8; ++i)
                bf[i] = wp[(size_t)(kt * 32 + i) * DDIM];
            union { bf16x8 v; unsigned u[4]; } BH, BL;
            #pragma unroll
            for (int i = 0; i < 4; ++i) {
                const unsigned u0 = __float_as_uint(bf[2 * i]);
                const unsigned u1 = __float_as_uint(bf[2 * i + 1]);
                BH.u[i] = __builtin_amdgcn_perm(u1, u0, 0x07060302u);
                const float l0 = bf[2 * i]     - __uint_as_float(u0 & 0xFFFF0000u);
                const float l1 = bf[2 * i + 1] - __uint_as_float(u1 & 0xFFFF0000u);
                BL.u[i] = __builtin_amdgcn_perm(__float_as_uint(l1), __float_as_uint(l0),
                                                0x07060302u);
            }
            f32x4 a = (df == 0) ? acc0 : acc1;
            a = __builtin_amdgcn_mfma_f32_16x16x32_bf16(AH.v, BH.v, a, 0, 0, 0);
            a = __builtin_amdgcn_mfma_f32_16x16x32_bf16(AH.v, BL.v, a, 0, 0, 0);
            a = __builtin_amdgcn_mfma_f32_16x16x32_bf16(AL.v, BH.v, a, 0, 0, 0);
            if (df == 0) acc0 = a; else acc1 = a;
        }
    }

    // C/D layout: col = lane&15, row = (lane>>4)*4 + reg  [m89-verified]
    #pragma unroll
    for (int r = 0; r < 4; ++r) {
        Pr[g * 4 + r][dq +  0 + l15] = acc0[r];
        Pr[g * 4 + r][dq + 16 + l15] = acc1[r];
    }
    __syncthreads();

    // Snapshot both pr rows, then Pr's LDS is recycled as staging space.
    const float4 prA = *reinterpret_cast<const float4*>(&Pr[w * 2 + 0][lane * 4]);
    const float4 prB = *reinterpret_cast<const float4*>(&Pr[w * 2 + 1][lane * 4]);
    __syncthreads();

    // ---------------- Phase B: attention, 2 pids per wave -----------------
    #pragma unroll 1
    for (int pp = 0; pp < 2; ++pp) {
        const int pl  = w * 2 + pp;            // pid-local 0..15
        const int pid = pid0 + pl;
        const int b   = pid >> 10;             // / NPTS
        const float4 pr = pp ? prB : prA;
        const float2 ppos = *reinterpret_cast<const float2*>(&p_t[pid * 2]);
        const float p0f = ppos.x;
        const float p1f = ppos.y;
        const int p0 = (int)p0f;
        const int p1 = (int)p1f;

        float re[3], ce[5];
        int rowidx[3], colidx[5];
        #pragma unroll
        for (int i = 0; i < 3; ++i) {
            int rr = p0 + i;
            rr = rr > ROWS ? ROWS : rr;
            rr = (rr == ROWS) ? 0 : rr;        // % ROWS
            rowidx[i] = rr;
            const float rf = (float)(rr - 1 > 0 ? rr - 1 : 0);
            const float dr = rf - p0f;         // / R_WIN (=1)
            re[i] = __expf(-2.0f * dr * dr);
        }
        #pragma unroll
        for (int j = 0; j < 5; ++j) {
            int cc = p1 + j - 1;
            cc = cc < 0 ? 0 : (cc > COLS ? COLS : cc);
            cc = (cc == COLS) ? 0 : cc;        // % COLS
            colidx[j] = cc;
            const float cf = (float)(cc - 1 > 0 ? cc - 1 : 0);
            const float dc = (cf - p1f) * 0.5f; // / C_WIN (=2)
            ce[j] = __expf(-2.0f * dc * dc);
        }

        // Fence: previous round's LDS reads must retire before async writes
        // to the same slab can be issued (vmcnt and lgkmcnt are separate).
        asm volatile("s_waitcnt lgkmcnt(0)" ::: "memory");
        __builtin_amdgcn_sched_barrier(0);

        // ---- Issue ALL 15 gathers: rows 0..NREG-1 -> regs, rest -> LDS ----
        float4 qg[NREG];
        unsigned vmask = 0;
        #pragma unroll
        for (int k = 0; k < KWIN; ++k) {
            const int i = k / 5, j = k % 5;
            const int rr = rowidx[i];
            const int cc = colidx[j];
            const bool valid = (rr != 0) && (cc != 0);   // wave-uniform
            const float* src =
                &q[((size_t)((b * HGRID + rr - 1) * WGRID + cc - 1)) * DDIM + lane * 4];
            if (k < NREG) {
                float4 v = make_float4(0.f, 0.f, 0.f, 0.f);
                if (valid) v = *reinterpret_cast<const float4*>(src);
                qg[k] = v;
            } else {
                if (valid) gload_lds16(src, &qsw[(k - NREG) * DDIM]);
            }
            if (valid) vmask |= (1u << k);
        }
        asm volatile("s_waitcnt vmcnt(0)" ::: "memory");   // ONE wait for all 15
        // Pin register rows once (post-drain: no serialization, no remat).
        #pragma unroll
        for (int k = 0; k < NREG; ++k)
            asm volatile("" : "+v"(qg[k].x), "+v"(qg[k].y), "+v"(qg[k].z), "+v"(qg[k].w));

        // ---- Scores ----
        float score[KWIN];
        #pragma unroll
        for (int k = 0; k < NREG; ++k) {
            const float4 v = qg[k];
            score[k] = fmaf(v.x, pr.x, fmaf(v.y, pr.y, fmaf(v.z, pr.z, v.w * pr.w)));
        }
        #pragma unroll
        for (int k = NREG; k < KWIN; ++k) {
            const float4 v =
                *reinterpret_cast<const float4*>(&qsw[(k - NREG) * DDIM + lane * 4]);
            score[k] = fmaf(v.x, pr.x, fmaf(v.y, pr.y, fmaf(v.z, pr.z, v.w * pr.w)));
        }

        // ---- 15 independent butterfly reductions ----
        #pragma unroll
        for (int k = 0; k < KWIN; ++k) {
            float s = score[k];
            #pragma unroll
            for (int off = 32; off; off >>= 1) s += __shfl_xor(s, off, 64);
            score[k] = ((vmask >> k) & 1u) ? s : -INFINITY;
        }

        // ---- Softmax over K=15 (replicated across lanes) ----
        float mx = score[0];
        #pragma unroll
        for (int k = 1; k < KWIN; ++k) mx = fmaxf(mx, score[k]);
        float sum = 0.f;
        #pragma unroll
        for (int k = 0; k < KWIN; ++k) {
            const float e = __expf(score[k] - mx);
            score[k] = e;
            sum += e;
        }
        const float inv = 1.0f / sum;

        // ---- Weighted sum: reg rows + LDS rows ----
        float ox = 0.f, oy = 0.f, oz = 0.f, ow = 0.f;
        #pragma unroll
        for (int k = 0; k < KWIN; ++k) {
            const int i = k / 5, j = k % 5;
            const float wk2 = score[k] * inv * re[i] * ce[j];
            if (k < NREG) {
                ox = fmaf(wk2, qg[k].x, ox);
                oy = fmaf(wk2, qg[k].y, oy);
                oz = fmaf(wk2, qg[k].z, oz);
                ow = fmaf(wk2, qg[k].w, ow);
            } else if ((vmask >> k) & 1u) {   // guard: stale LDS may be NaN
                const float4 v =
                    *reinterpret_cast<const float4*>(&qsw[(k - NREG) * DDIM + lane * 4]);
                ox = fmaf(wk2, v.x, ox);
                oy = fmaf(wk2, v.y, oy);
                oz = fmaf(wk2, v.z, oz);
                ow = fmaf(wk2, v.w, ow);
            }
        }
        *reinterpret_cast<float4*>(&out[(size_t)pid * DDIM + lane * 4]) =
            make_float4(ox, oy, oz, ow);
    }
}

// ---------------------------------------------------------------------------
extern "C" void kernel_launch(void* const* d_in, const int* in_sizes, int n_in,
                              void* d_out, int out_size, void* d_ws, size_t ws_size,
                              hipStream_t stream) {
    const float* q   = (const float*)d_in[0];
    const float* c_t = (const float*)d_in[1];
    const float* p_t = (const float*)d_in[2];
    const float* W_a = (const float*)d_in[3];
    float* out = (float*)d_out;

    fused_local_attn<<<BN / PIDS_PER_BLK, THREADS, 0, stream>>>(q, c_t, p_t, W_a, out);
}